// Round 1
// baseline (4982.286 us; speedup 1.0000x reference)
//
#include <hip/hip_runtime.h>
#include <hip/hip_bf16.h>

// Decoder: T=32 steps, B=64, S=256, DEC=ENC=ATT=WV=512, V=32000, POOL=2
// Round 1: correctness-first f32 baseline.
//   ws layout (floats):
//     pre      [64][256][512]  @ 0         (8388608)
//     gxe      [2048][1536]    @ 8388608   (3145728)   emb-part of gates + b_ih
//     h_hist   [32][64][512]   @ 11534336  (1048576)
//     ctx_hist [32][64][512]   @ 12582912  (1048576)
//     target   [64][512]       @ 13631488  (32768)
//     energy   [64][256]       @ 13664256  (16384)   -> total 13680640 floats (54.7MB)

#define BB 64
#define DD 512
#define G3 1536

__device__ __forceinline__ float sigmf(float x) { return 1.0f / (1.0f + __expf(-x)); }
__device__ __forceinline__ float tanh_fast(float x) {
    float e = __expf(2.0f * x);
    return 1.0f - 2.0f / (e + 1.0f);
}

// ---------------- batched GEMM: C[M,N] = A[M,K] @ B[N,K]^T + bias ----------------
// MODE 0: A row m -> context[s][b][:] with m = b*256+s   (precompute)
// MODE 1: A row m -> emb_table[ids[m]][:]                (emb part of gates)
template <int MODE>
__global__ __launch_bounds__(256) void gemm128(
    const float* __restrict__ A0, const float* __restrict__ Bm,
    const float* __restrict__ bias, float* __restrict__ C,
    const int* __restrict__ ids, int K, int ldb, int ldc)
{
    __shared__ float As[16][128];
    __shared__ float Bs[16][128];
    const int tid = threadIdx.x;
    const int tx = tid & 15, ty = tid >> 4;
    const int m0 = blockIdx.x * 128, n0 = blockIdx.y * 128;
    float acc[8][8] = {};
    for (int k0 = 0; k0 < K; k0 += 16) {
        __syncthreads();
#pragma unroll
        for (int q = 0; q < 2; ++q) {
            int f = q * 256 + tid;
            int row = f >> 2, kq = (f & 3) * 4;
            int m = m0 + row;
            const float* ap;
            if (MODE == 0) {
                int b = m >> 8, s = m & 255;
                ap = A0 + (size_t)s * (BB * DD) + (size_t)b * DD + k0 + kq;
            } else {
                ap = A0 + (size_t)ids[m] * DD + k0 + kq;
            }
            float4 v = *(const float4*)ap;
            As[kq + 0][row] = v.x; As[kq + 1][row] = v.y;
            As[kq + 2][row] = v.z; As[kq + 3][row] = v.w;
            float4 w = *(const float4*)(Bm + (size_t)(n0 + row) * ldb + k0 + kq);
            Bs[kq + 0][row] = w.x; Bs[kq + 1][row] = w.y;
            Bs[kq + 2][row] = w.z; Bs[kq + 3][row] = w.w;
        }
        __syncthreads();
#pragma unroll
        for (int kk = 0; kk < 16; ++kk) {
            float4 a0 = *(const float4*)&As[kk][ty * 8];
            float4 a1 = *(const float4*)&As[kk][ty * 8 + 4];
            float4 b0 = *(const float4*)&Bs[kk][tx * 8];
            float4 b1 = *(const float4*)&Bs[kk][tx * 8 + 4];
            float ar[8] = {a0.x, a0.y, a0.z, a0.w, a1.x, a1.y, a1.z, a1.w};
            float br[8] = {b0.x, b0.y, b0.z, b0.w, b1.x, b1.y, b1.z, b1.w};
#pragma unroll
            for (int r = 0; r < 8; ++r)
#pragma unroll
                for (int c = 0; c < 8; ++c)
                    acc[r][c] = fmaf(ar[r], br[c], acc[r][c]);
        }
    }
    float bs[8];
#pragma unroll
    for (int c = 0; c < 8; ++c) bs[c] = bias[n0 + tx * 8 + c];
#pragma unroll
    for (int r = 0; r < 8; ++r) {
        float* crow = C + (size_t)(m0 + ty * 8 + r) * ldc + n0 + tx * 8;
        float4 o0 = make_float4(acc[r][0] + bs[0], acc[r][1] + bs[1],
                                acc[r][2] + bs[2], acc[r][3] + bs[3]);
        float4 o1 = make_float4(acc[r][4] + bs[4], acc[r][5] + bs[5],
                                acc[r][6] + bs[6], acc[r][7] + bs[7]);
        *(float4*)crow = o0;
        *(float4*)(crow + 4) = o1;
    }
}

// ---------------- per-step GRU cell ----------------
// grid 128 (4 h-dims per block), 256 threads: lane->b, wave->i (d = blk*4+i)
__global__ __launch_bounds__(256) void k_gru(
    int t, const float* __restrict__ gxe,
    const float* __restrict__ ctx_prev, const float* __restrict__ h_prev,
    const float* __restrict__ W_ih, const float* __restrict__ W_hh,
    const float* __restrict__ b_hh, float* __restrict__ h_out)
{
    __shared__ float Xs[64 * 65];
    const int tid = threadIdx.x;
    const int b = tid & 63;
    const int i = __builtin_amdgcn_readfirstlane(tid >> 6);
    const int d = blockIdx.x * 4 + i;
    const size_t m = (size_t)t * 64 + b;
    float ax0 = gxe[m * G3 + d];
    float ax1 = gxe[m * G3 + 512 + d];
    float ax2 = gxe[m * G3 + 1024 + d];
    float ah0 = b_hh[d], ah1 = b_hh[512 + d], ah2 = b_hh[1024 + d];
    // ctx part of gx: W_ih columns 512..1023 (wave-uniform rows -> scalar loads)
    const float* w0 = W_ih + (size_t)d * 1024 + 512;
    const float* w1 = W_ih + (size_t)(512 + d) * 1024 + 512;
    const float* w2 = W_ih + (size_t)(1024 + d) * 1024 + 512;
    for (int kc = 0; kc < 512; kc += 64) {
        __syncthreads();
#pragma unroll
        for (int q = 0; q < 16; ++q) {
            int idx = q * 256 + tid;
            int k = idx & 63, bb = idx >> 6;
            Xs[k * 65 + bb] = ctx_prev[(size_t)bb * DD + kc + k];
        }
        __syncthreads();
#pragma unroll
        for (int k = 0; k < 64; ++k) {
            float xv = Xs[k * 65 + b];
            ax0 = fmaf(xv, w0[kc + k], ax0);
            ax1 = fmaf(xv, w1[kc + k], ax1);
            ax2 = fmaf(xv, w2[kc + k], ax2);
        }
    }
    const float* u0 = W_hh + (size_t)d * 512;
    const float* u1 = W_hh + (size_t)(512 + d) * 512;
    const float* u2 = W_hh + (size_t)(1024 + d) * 512;
    for (int kc = 0; kc < 512; kc += 64) {
        __syncthreads();
#pragma unroll
        for (int q = 0; q < 16; ++q) {
            int idx = q * 256 + tid;
            int k = idx & 63, bb = idx >> 6;
            Xs[k * 65 + bb] = h_prev[(size_t)bb * DD + kc + k];
        }
        __syncthreads();
#pragma unroll
        for (int k = 0; k < 64; ++k) {
            float xv = Xs[k * 65 + b];
            ah0 = fmaf(xv, u0[kc + k], ah0);
            ah1 = fmaf(xv, u1[kc + k], ah1);
            ah2 = fmaf(xv, u2[kc + k], ah2);
        }
    }
    float r = sigmf(ax0 + ah0);
    float z = sigmf(ax1 + ah1);
    float n = tanh_fast(ax2 + r * ah2);
    float hp = h_prev[(size_t)b * DD + d];
    h_out[(size_t)b * DD + d] = (1.0f - z) * n + z * hp;
}

// ---------------- per-step target = h @ W_q^T ----------------
__global__ __launch_bounds__(256) void k_target(
    const float* __restrict__ h_cur, const float* __restrict__ W_q,
    float* __restrict__ target)
{
    __shared__ float Xs[64 * 65];
    const int tid = threadIdx.x;
    const int b = tid & 63;
    const int i = __builtin_amdgcn_readfirstlane(tid >> 6);
    const int a = blockIdx.x * 4 + i;
    const float* wq = W_q + (size_t)a * 512;
    float acc = 0.f;
    for (int kc = 0; kc < 512; kc += 64) {
        __syncthreads();
#pragma unroll
        for (int q = 0; q < 16; ++q) {
            int idx = q * 256 + tid;
            int k = idx & 63, bb = idx >> 6;
            Xs[k * 65 + bb] = h_cur[(size_t)bb * DD + kc + k];
        }
        __syncthreads();
#pragma unroll
        for (int k = 0; k < 64; ++k)
            acc = fmaf(Xs[k * 65 + b], wq[kc + k], acc);
    }
    target[(size_t)b * DD + a] = acc;
}

// ---------------- per-step energy[b][s] = v . tanh(pre + tgt), masked ----------------
// grid 256 = (b, s-chunk of 64); wave handles one s at a time, lanes split a.
__global__ __launch_bounds__(256) void k_energy(
    const float* __restrict__ pre, const float* __restrict__ target,
    const float* __restrict__ v_att, const float* __restrict__ mask,
    float* __restrict__ energy)
{
    __shared__ float tg[512], vv[512];
    const int tid = threadIdx.x;
    const int b = blockIdx.x >> 2, sc4 = blockIdx.x & 3;
    if (tid < 128) ((float4*)tg)[tid] = ((const float4*)(target + (size_t)b * DD))[tid];
    else           ((float4*)vv)[tid - 128] = ((const float4*)v_att)[tid - 128];
    __syncthreads();
    const int lane = tid & 63, wid = tid >> 6;
    const float4* tg4 = (const float4*)tg;
    const float4* vv4 = (const float4*)vv;
    float4 t0 = tg4[lane * 2], t1 = tg4[lane * 2 + 1];
    float4 v0 = vv4[lane * 2], v1 = vv4[lane * 2 + 1];
    for (int si = 0; si < 16; ++si) {
        int s = sc4 * 64 + wid * 16 + si;
        const float4* pp = (const float4*)(pre + ((size_t)b * 256 + s) * 512 + lane * 8);
        float4 p0 = pp[0], p1 = pp[1];
        float sum = v0.x * tanh_fast(p0.x + t0.x) + v0.y * tanh_fast(p0.y + t0.y) +
                    v0.z * tanh_fast(p0.z + t0.z) + v0.w * tanh_fast(p0.w + t0.w) +
                    v1.x * tanh_fast(p1.x + t1.x) + v1.y * tanh_fast(p1.y + t1.y) +
                    v1.z * tanh_fast(p1.z + t1.z) + v1.w * tanh_fast(p1.w + t1.w);
#pragma unroll
        for (int off = 1; off < 64; off <<= 1) sum += __shfl_xor(sum, off);
        if (lane == 0) {
            float mk = mask[(size_t)b * 256 + s];
            energy[(size_t)b * 256 + s] = sum * (1.0f - mk) + mk * (-1e6f);
        }
    }
}

// ---------------- per-step softmax + context GEMV ----------------
// grid 256 = (b, e-chunk of 128). Softmax computed redundantly per block.
__global__ __launch_bounds__(256) void k_ctx(
    int t, const float* __restrict__ energy, const float* __restrict__ context,
    float* __restrict__ ctx_hist, float* __restrict__ cout)
{
    __shared__ float score_sh[256];
    __shared__ float psh[256];
    __shared__ float wred[4], wred2[4];
    const int tid = threadIdx.x;
    const int b = blockIdx.x >> 2, ec = blockIdx.x & 3;
    const int lane = tid & 63, wid = tid >> 6;
    float e = energy[(size_t)b * 256 + tid];
    float mx = e;
#pragma unroll
    for (int off = 1; off < 64; off <<= 1) mx = fmaxf(mx, __shfl_xor(mx, off));
    if (lane == 0) wred[wid] = mx;
    __syncthreads();
    mx = fmaxf(fmaxf(wred[0], wred[1]), fmaxf(wred[2], wred[3]));
    float ex = __expf(e - mx);
    float sm = ex;
#pragma unroll
    for (int off = 1; off < 64; off <<= 1) sm += __shfl_xor(sm, off);
    if (lane == 0) wred2[wid] = sm;
    __syncthreads();
    sm = wred2[0] + wred2[1] + wred2[2] + wred2[3];
    float sc = ex / sm;
    score_sh[tid] = sc;
    if (ec == 0) cout[((size_t)t * 64 + b) * 256 + tid] = sc;
    __syncthreads();
    int j = tid & 127, half = tid >> 7;
    const float* cb = context + (size_t)(half * 128) * (BB * DD) + (size_t)b * DD + ec * 128 + j;
    float s = 0.f;
#pragma unroll 4
    for (int ss = 0; ss < 128; ++ss)
        s = fmaf(score_sh[half * 128 + ss], cb[(size_t)ss * (BB * DD)], s);
    psh[tid] = s;
    __syncthreads();
    if (tid < 128)
        ctx_hist[(size_t)t * (BB * DD) + (size_t)b * DD + ec * 128 + tid] =
            psh[tid] + psh[tid + 128];
}

// ---------------- batched readout + maxout ----------------
// M=2048 rows (t*64+b), N=512 -> 256 after pool. BM=64, BN=128.
__global__ __launch_bounds__(256) void k_readout(
    const float* __restrict__ emb_table, const int* __restrict__ ids,
    const float* __restrict__ h_hist, const float* __restrict__ ctx_hist,
    const float* __restrict__ W_read, const float* __restrict__ b_read,
    float* __restrict__ gout)
{
    __shared__ float As[16][64];
    __shared__ float Bs[16][128];
    const int tid = threadIdx.x;
    const int tx = tid & 15, ty = tid >> 4;
    const int m0 = blockIdx.x * 64, n0 = blockIdx.y * 128;
    float acc[4][8] = {};
    for (int k0 = 0; k0 < G3; k0 += 16) {
        __syncthreads();
        {
            int row = tid >> 2, kq = (tid & 3) * 4;
            int m = m0 + row, k = k0 + kq;
            const float* ap;
            if (k < 512)       ap = emb_table + (size_t)ids[m] * DD + k;
            else if (k < 1024) ap = h_hist + (size_t)m * DD + (k - 512);
            else               ap = ctx_hist + (size_t)m * DD + (k - 1024);
            float4 v = *(const float4*)ap;
            As[kq + 0][row] = v.x; As[kq + 1][row] = v.y;
            As[kq + 2][row] = v.z; As[kq + 3][row] = v.w;
        }
#pragma unroll
        for (int q = 0; q < 2; ++q) {
            int f = q * 256 + tid;
            int row = f >> 2, kq = (f & 3) * 4;
            float4 w = *(const float4*)(W_read + (size_t)(n0 + row) * G3 + k0 + kq);
            Bs[kq + 0][row] = w.x; Bs[kq + 1][row] = w.y;
            Bs[kq + 2][row] = w.z; Bs[kq + 3][row] = w.w;
        }
        __syncthreads();
#pragma unroll
        for (int kk = 0; kk < 16; ++kk) {
            float4 a = *(const float4*)&As[kk][ty * 4];
            float4 b0 = *(const float4*)&Bs[kk][tx * 8];
            float4 b1 = *(const float4*)&Bs[kk][tx * 8 + 4];
            float ar[4] = {a.x, a.y, a.z, a.w};
            float br[8] = {b0.x, b0.y, b0.z, b0.w, b1.x, b1.y, b1.z, b1.w};
#pragma unroll
            for (int r = 0; r < 4; ++r)
#pragma unroll
                for (int c = 0; c < 8; ++c)
                    acc[r][c] = fmaf(ar[r], br[c], acc[r][c]);
        }
    }
    float bs[8];
#pragma unroll
    for (int c = 0; c < 8; ++c) bs[c] = b_read[n0 + tx * 8 + c];
#pragma unroll
    for (int r = 0; r < 4; ++r) {
        int m = m0 + ty * 4 + r;
        float v[8];
#pragma unroll
        for (int c = 0; c < 8; ++c) v[c] = acc[r][c] + bs[c];
        float4 o = make_float4(fmaxf(v[0], v[1]), fmaxf(v[2], v[3]),
                               fmaxf(v[4], v[5]), fmaxf(v[6], v[7]));
        *(float4*)(gout + (size_t)m * 256 + (n0 >> 1) + tx * 4) = o;
    }
}

// ---------------- batched copy gate ----------------
__global__ __launch_bounds__(256) void k_copy(
    const float* __restrict__ h_hist, const float* __restrict__ ctx_hist,
    const float* __restrict__ W_copy, const float* __restrict__ b_copy,
    float* __restrict__ out)
{
    const int tid = threadIdx.x;
    const int lane = tid & 63;
    const int tb = blockIdx.x * 4 + (tid >> 6);
    const float* hp = h_hist + (size_t)tb * DD;
    const float* cp = ctx_hist + (size_t)tb * DD;
    float acc = 0.f;
#pragma unroll
    for (int j = 0; j < 8; ++j) {
        int k = lane + 64 * j;
        acc = fmaf(hp[k], W_copy[k], acc);
        acc = fmaf(cp[k], W_copy[512 + k], acc);
    }
#pragma unroll
    for (int off = 1; off < 64; off <<= 1) acc += __shfl_xor(acc, off);
    if (lane == 0) out[tb] = sigmf(acc + b_copy[0]);
}

// ---------------- tail outputs (hid, c_out[-1], cur_ctx) ----------------
__global__ void k_final(const float* __restrict__ h_hist,
                        const float* __restrict__ ctx_hist,
                        float* __restrict__ dout)
{
    int idx = blockIdx.x * 256 + threadIdx.x;
    if (idx < 32768) {
        dout[1050624 + idx] = h_hist[31 * 32768 + idx];
    } else if (idx < 49152) {
        int i2 = idx - 32768;
        dout[1083392 + i2] = dout[524288 + 507904 + i2];
    } else {
        int i2 = idx - 49152;
        dout[1099776 + i2] = ctx_hist[31 * 32768 + i2];
    }
}

extern "C" void kernel_launch(void* const* d_in, const int* in_sizes, int n_in,
                              void* d_out, int out_size, void* d_ws, size_t ws_size,
                              hipStream_t stream)
{
    (void)in_sizes; (void)n_in; (void)out_size; (void)ws_size;
    const int*   ids      = (const int*)d_in[0];
    const float* hidden   = (const float*)d_in[1];
    const float* context  = (const float*)d_in[2];
    const float* mask     = (const float*)d_in[3];
    const float* init_att = (const float*)d_in[4];
    const float* emb_t    = (const float*)d_in[5];
    const float* W_ih     = (const float*)d_in[6];
    const float* W_hh     = (const float*)d_in[7];
    const float* b_ih     = (const float*)d_in[8];
    const float* b_hh     = (const float*)d_in[9];
    const float* W_pre    = (const float*)d_in[10];
    const float* b_pre    = (const float*)d_in[11];
    const float* W_q      = (const float*)d_in[12];
    const float* v_att    = (const float*)d_in[13];
    const float* W_copy   = (const float*)d_in[14];
    const float* b_copy   = (const float*)d_in[15];
    const float* W_read   = (const float*)d_in[16];
    const float* b_read   = (const float*)d_in[17];
    float* out = (float*)d_out;
    float* ws = (float*)d_ws;

    float* pre      = ws;
    float* gxe      = ws + 8388608;
    float* h_hist   = ws + 11534336;
    float* ctx_hist = ws + 12582912;
    float* target   = ws + 13631488;
    float* energy   = ws + 13664256;

    // precompute[b][s][a] = ctx_t @ W_pre^T + b_pre
    gemm128<0><<<dim3(128, 4), 256, 0, stream>>>(context, W_pre, b_pre, pre, nullptr,
                                                 512, 512, 512);
    // gxe[t*64+b][j] = emb @ W_ih[:, :512]^T + b_ih
    gemm128<1><<<dim3(16, 12), 256, 0, stream>>>(emb_t, W_ih, b_ih, gxe, ids,
                                                 512, 1024, 1536);
    for (int t = 0; t < 32; ++t) {
        const float* ctx_prev = t ? ctx_hist + (size_t)(t - 1) * 32768 : init_att;
        const float* h_prev   = t ? h_hist + (size_t)(t - 1) * 32768 : hidden;
        k_gru<<<128, 256, 0, stream>>>(t, gxe, ctx_prev, h_prev, W_ih, W_hh, b_hh,
                                       h_hist + (size_t)t * 32768);
        k_target<<<128, 256, 0, stream>>>(h_hist + (size_t)t * 32768, W_q, target);
        k_energy<<<256, 256, 0, stream>>>(pre, target, v_att, mask, energy);
        k_ctx<<<256, 256, 0, stream>>>(t, energy, context, ctx_hist, out + 524288);
    }
    k_readout<<<dim3(32, 4), 256, 0, stream>>>(emb_t, ids, h_hist, ctx_hist,
                                               W_read, b_read, out);
    k_copy<<<512, 256, 0, stream>>>(h_hist, ctx_hist, W_copy, b_copy, out + 1048576);
    k_final<<<320, 256, 0, stream>>>(h_hist, ctx_hist, out);
}

// Round 2
// 4940.587 us; speedup vs baseline: 1.0084x; 1.0084x over previous
//
#include <hip/hip_runtime.h>
#include <hip/hip_bf16.h>
#include <hip/hip_cooperative_groups.h>

namespace cg = cooperative_groups;

// Decoder: T=32 steps, B=64, S=256, DEC=ENC=ATT=WV=512, V=32000, POOL=2
// Round 2: fuse the 32-step loop into ONE cooperative kernel (grid.sync between
// phases) to remove 128 sequential launches; pad GEMM LDS tiles to kill bank
// conflicts. All f32.
//   ws layout (floats):
//     pre      [64][256][512]  @ 0         (8388608)
//     gxe      [2048][1536]    @ 8388608   (3145728)
//     h_hist   [32][64][512]   @ 11534336  (1048576)
//     ctx_hist [32][64][512]   @ 12582912  (1048576)
//     target   [64][512]       @ 13631488  (32768)
//     energy   [64][256]       @ 13664256  (16384)

#define BB 64
#define DD 512
#define G3 1536

__device__ __forceinline__ float sigmf(float x) { return 1.0f / (1.0f + __expf(-x)); }
__device__ __forceinline__ float tanh_fast(float x) {
    float e = __expf(2.0f * x);
    return 1.0f - 2.0f / (e + 1.0f);
}

// ---------------- batched GEMM: C[M,N] = A[M,K] @ B[N,K]^T + bias ----------------
// MODE 0: A row m -> context[s][b][:] with m = b*256+s   (precompute)
// MODE 1: A row m -> emb_table[ids[m]][:]                (emb part of gates)
template <int MODE>
__global__ __launch_bounds__(256) void gemm128(
    const float* __restrict__ A0, const float* __restrict__ Bm,
    const float* __restrict__ bias, float* __restrict__ C,
    const int* __restrict__ ids, int K, int ldb, int ldc)
{
    __shared__ float As[16][132];   // pad 132: store-bank-conflict-free (132%32==4)
    __shared__ float Bs[16][132];
    const int tid = threadIdx.x;
    const int tx = tid & 15, ty = tid >> 4;
    const int m0 = blockIdx.x * 128, n0 = blockIdx.y * 128;
    float acc[8][8] = {};
    for (int k0 = 0; k0 < K; k0 += 16) {
        __syncthreads();
#pragma unroll
        for (int q = 0; q < 2; ++q) {
            int f = q * 256 + tid;
            int row = f >> 2, kq = (f & 3) * 4;
            int m = m0 + row;
            const float* ap;
            if (MODE == 0) {
                int b = m >> 8, s = m & 255;
                ap = A0 + (size_t)s * (BB * DD) + (size_t)b * DD + k0 + kq;
            } else {
                ap = A0 + (size_t)ids[m] * DD + k0 + kq;
            }
            float4 v = *(const float4*)ap;
            As[kq + 0][row] = v.x; As[kq + 1][row] = v.y;
            As[kq + 2][row] = v.z; As[kq + 3][row] = v.w;
            float4 w = *(const float4*)(Bm + (size_t)(n0 + row) * ldb + k0 + kq);
            Bs[kq + 0][row] = w.x; Bs[kq + 1][row] = w.y;
            Bs[kq + 2][row] = w.z; Bs[kq + 3][row] = w.w;
        }
        __syncthreads();
#pragma unroll
        for (int kk = 0; kk < 16; ++kk) {
            float4 a0 = *(const float4*)&As[kk][ty * 8];
            float4 a1 = *(const float4*)&As[kk][ty * 8 + 4];
            float4 b0 = *(const float4*)&Bs[kk][tx * 8];
            float4 b1 = *(const float4*)&Bs[kk][tx * 8 + 4];
            float ar[8] = {a0.x, a0.y, a0.z, a0.w, a1.x, a1.y, a1.z, a1.w};
            float br[8] = {b0.x, b0.y, b0.z, b0.w, b1.x, b1.y, b1.z, b1.w};
#pragma unroll
            for (int r = 0; r < 8; ++r)
#pragma unroll
                for (int c = 0; c < 8; ++c)
                    acc[r][c] = fmaf(ar[r], br[c], acc[r][c]);
        }
    }
    float bs[8];
#pragma unroll
    for (int c = 0; c < 8; ++c) bs[c] = bias[n0 + tx * 8 + c];
#pragma unroll
    for (int r = 0; r < 8; ++r) {
        float* crow = C + (size_t)(m0 + ty * 8 + r) * ldc + n0 + tx * 8;
        float4 o0 = make_float4(acc[r][0] + bs[0], acc[r][1] + bs[1],
                                acc[r][2] + bs[2], acc[r][3] + bs[3]);
        float4 o1 = make_float4(acc[r][4] + bs[4], acc[r][5] + bs[5],
                                acc[r][6] + bs[6], acc[r][7] + bs[7]);
        *(float4*)crow = o0;
        *(float4*)(crow + 4) = o1;
    }
}

// ---------------- cooperative 32-step loop ----------------
// grid = 128 blocks x 256 threads, all co-resident. 4 phases/step:
//  P1 GRU (block g -> 4 h-dims, wave i -> d=g*4+i, lane -> b)
//  P2 target (same split over a)
//  P3 energy (block -> (b, s-half of 128), wave -> 32 s, lanes split a)
//  P4 softmax + ctx GEMV (block -> (b, e-half of 256), thread -> e)
__global__ __launch_bounds__(256) void k_steps(
    const float* __restrict__ gxe, const float* __restrict__ hidden,
    const float* __restrict__ init_att,
    const float* __restrict__ W_ih, const float* __restrict__ W_hh,
    const float* __restrict__ b_hh, const float* __restrict__ W_q,
    const float* __restrict__ pre, const float* __restrict__ v_att,
    const float* __restrict__ mask, const float* __restrict__ context,
    float* __restrict__ h_hist, float* __restrict__ ctx_hist,
    float* __restrict__ target, float* __restrict__ energy,
    float* __restrict__ cout)
{
    cg::grid_group grid = cg::this_grid();
    __shared__ float sh[64 * 65];        // 16.6 KB, reused across phases
    const int tid = threadIdx.x;
    const int g = blockIdx.x;
    const int lane = tid & 63;
    const int wid = __builtin_amdgcn_readfirstlane(tid >> 6);

    for (int t = 0; t < 32; ++t) {
        const float* ctx_prev = t ? ctx_hist + (size_t)(t - 1) * 32768 : init_att;
        const float* h_prev   = t ? h_hist + (size_t)(t - 1) * 32768 : hidden;
        float* h_cur = h_hist + (size_t)t * 32768;

        // ---- P1: GRU ----
        {
            const int b = lane;
            const int d = g * 4 + wid;
            const size_t m = (size_t)t * 64 + b;
            float ax0 = gxe[m * G3 + d];
            float ax1 = gxe[m * G3 + 512 + d];
            float ax2 = gxe[m * G3 + 1024 + d];
            float ah0 = b_hh[d], ah1 = b_hh[512 + d], ah2 = b_hh[1024 + d];
            const float* w0 = W_ih + (size_t)d * 1024 + 512;
            const float* w1 = W_ih + (size_t)(512 + d) * 1024 + 512;
            const float* w2 = W_ih + (size_t)(1024 + d) * 1024 + 512;
            for (int kc = 0; kc < 512; kc += 64) {
                __syncthreads();
#pragma unroll
                for (int q = 0; q < 16; ++q) {
                    int idx = q * 256 + tid;
                    int k = idx & 63, bb = idx >> 6;
                    sh[k * 65 + bb] = ctx_prev[(size_t)bb * DD + kc + k];
                }
                __syncthreads();
#pragma unroll
                for (int k = 0; k < 64; ++k) {
                    float xv = sh[k * 65 + b];
                    ax0 = fmaf(xv, w0[kc + k], ax0);
                    ax1 = fmaf(xv, w1[kc + k], ax1);
                    ax2 = fmaf(xv, w2[kc + k], ax2);
                }
            }
            const float* u0 = W_hh + (size_t)d * 512;
            const float* u1 = W_hh + (size_t)(512 + d) * 512;
            const float* u2 = W_hh + (size_t)(1024 + d) * 512;
            for (int kc = 0; kc < 512; kc += 64) {
                __syncthreads();
#pragma unroll
                for (int q = 0; q < 16; ++q) {
                    int idx = q * 256 + tid;
                    int k = idx & 63, bb = idx >> 6;
                    sh[k * 65 + bb] = h_prev[(size_t)bb * DD + kc + k];
                }
                __syncthreads();
#pragma unroll
                for (int k = 0; k < 64; ++k) {
                    float xv = sh[k * 65 + b];
                    ah0 = fmaf(xv, u0[kc + k], ah0);
                    ah1 = fmaf(xv, u1[kc + k], ah1);
                    ah2 = fmaf(xv, u2[kc + k], ah2);
                }
            }
            float r = sigmf(ax0 + ah0);
            float z = sigmf(ax1 + ah1);
            float n = tanh_fast(ax2 + r * ah2);
            float hp = h_prev[(size_t)b * DD + d];
            h_cur[(size_t)b * DD + d] = (1.0f - z) * n + z * hp;
        }
        grid.sync();

        // ---- P2: target = h @ W_q^T ----
        {
            const int b = lane;
            const int a = g * 4 + wid;
            const float* wq = W_q + (size_t)a * 512;
            float acc = 0.f;
            for (int kc = 0; kc < 512; kc += 64) {
                __syncthreads();
#pragma unroll
                for (int q = 0; q < 16; ++q) {
                    int idx = q * 256 + tid;
                    int k = idx & 63, bb = idx >> 6;
                    sh[k * 65 + bb] = h_cur[(size_t)bb * DD + kc + k];
                }
                __syncthreads();
#pragma unroll
                for (int k = 0; k < 64; ++k)
                    acc = fmaf(sh[k * 65 + b], wq[kc + k], acc);
            }
            target[(size_t)b * DD + a] = acc;
        }
        grid.sync();

        // ---- P3: energy[b][s] = v . tanh(pre + tgt), masked ----
        {
            const int b = g >> 1, shalf = g & 1;
            if (tid < 128)
                ((float4*)sh)[tid] = ((const float4*)(target + (size_t)b * DD))[tid];
            else
                ((float4*)(sh + 512))[tid - 128] = ((const float4*)v_att)[tid - 128];
            __syncthreads();
            const float4* tg4 = (const float4*)sh;
            const float4* vv4 = (const float4*)(sh + 512);
            float4 t0 = tg4[lane * 2], t1 = tg4[lane * 2 + 1];
            float4 v0 = vv4[lane * 2], v1 = vv4[lane * 2 + 1];
            for (int si = 0; si < 32; ++si) {
                int s = shalf * 128 + wid * 32 + si;
                const float4* pp =
                    (const float4*)(pre + ((size_t)b * 256 + s) * 512 + lane * 8);
                float4 p0 = pp[0], p1 = pp[1];
                float sum =
                    v0.x * tanh_fast(p0.x + t0.x) + v0.y * tanh_fast(p0.y + t0.y) +
                    v0.z * tanh_fast(p0.z + t0.z) + v0.w * tanh_fast(p0.w + t0.w) +
                    v1.x * tanh_fast(p1.x + t1.x) + v1.y * tanh_fast(p1.y + t1.y) +
                    v1.z * tanh_fast(p1.z + t1.z) + v1.w * tanh_fast(p1.w + t1.w);
#pragma unroll
                for (int off = 1; off < 64; off <<= 1) sum += __shfl_xor(sum, off);
                if (lane == 0) {
                    float mk = mask[(size_t)b * 256 + s];
                    energy[(size_t)b * 256 + s] = sum * (1.0f - mk) + mk * (-1e6f);
                }
            }
        }
        grid.sync();

        // ---- P4: softmax + ctx GEMV ----
        {
            const int b = g >> 1, eh = g & 1;
            float e = energy[(size_t)b * 256 + tid];
            float mx = e;
#pragma unroll
            for (int off = 1; off < 64; off <<= 1) mx = fmaxf(mx, __shfl_xor(mx, off));
            if (lane == 0) sh[4096 + wid] = mx;
            __syncthreads();
            mx = fmaxf(fmaxf(sh[4096], sh[4097]), fmaxf(sh[4098], sh[4099]));
            float ex = __expf(e - mx);
            float sm = ex;
#pragma unroll
            for (int off = 1; off < 64; off <<= 1) sm += __shfl_xor(sm, off);
            if (lane == 0) sh[4100 + wid] = sm;
            __syncthreads();
            sm = sh[4100] + sh[4101] + sh[4102] + sh[4103];
            float sc = ex / sm;
            sh[tid] = sc;
            if (eh == 0) cout[((size_t)t * 64 + b) * 256 + tid] = sc;
            __syncthreads();
            const int ee = eh * 256 + tid;
            float acc = 0.f;
#pragma unroll 16
            for (int s = 0; s < 256; ++s)
                acc = fmaf(sh[s], context[((size_t)s * 64 + b) * DD + ee], acc);
            ctx_hist[(size_t)t * 32768 + (size_t)b * DD + ee] = acc;
        }
        grid.sync();
    }
}

// ---------------- batched readout + maxout ----------------
__global__ __launch_bounds__(256) void k_readout(
    const float* __restrict__ emb_table, const int* __restrict__ ids,
    const float* __restrict__ h_hist, const float* __restrict__ ctx_hist,
    const float* __restrict__ W_read, const float* __restrict__ b_read,
    float* __restrict__ gout)
{
    __shared__ float As[16][68];
    __shared__ float Bs[16][132];
    const int tid = threadIdx.x;
    const int tx = tid & 15, ty = tid >> 4;
    const int m0 = blockIdx.x * 64, n0 = blockIdx.y * 128;
    float acc[4][8] = {};
    for (int k0 = 0; k0 < G3; k0 += 16) {
        __syncthreads();
        {
            int row = tid >> 2, kq = (tid & 3) * 4;
            int m = m0 + row, k = k0 + kq;
            const float* ap;
            if (k < 512)       ap = emb_table + (size_t)ids[m] * DD + k;
            else if (k < 1024) ap = h_hist + (size_t)m * DD + (k - 512);
            else               ap = ctx_hist + (size_t)m * DD + (k - 1024);
            float4 v = *(const float4*)ap;
            As[kq + 0][row] = v.x; As[kq + 1][row] = v.y;
            As[kq + 2][row] = v.z; As[kq + 3][row] = v.w;
        }
#pragma unroll
        for (int q = 0; q < 2; ++q) {
            int f = q * 256 + tid;
            int row = f >> 2, kq = (f & 3) * 4;
            float4 w = *(const float4*)(W_read + (size_t)(n0 + row) * G3 + k0 + kq);
            Bs[kq + 0][row] = w.x; Bs[kq + 1][row] = w.y;
            Bs[kq + 2][row] = w.z; Bs[kq + 3][row] = w.w;
        }
        __syncthreads();
#pragma unroll
        for (int kk = 0; kk < 16; ++kk) {
            float4 a = *(const float4*)&As[kk][ty * 4];
            float4 b0 = *(const float4*)&Bs[kk][tx * 8];
            float4 b1 = *(const float4*)&Bs[kk][tx * 8 + 4];
            float ar[4] = {a.x, a.y, a.z, a.w};
            float br[8] = {b0.x, b0.y, b0.z, b0.w, b1.x, b1.y, b1.z, b1.w};
#pragma unroll
            for (int r = 0; r < 4; ++r)
#pragma unroll
                for (int c = 0; c < 8; ++c)
                    acc[r][c] = fmaf(ar[r], br[c], acc[r][c]);
        }
    }
    float bs[8];
#pragma unroll
    for (int c = 0; c < 8; ++c) bs[c] = b_read[n0 + tx * 8 + c];
#pragma unroll
    for (int r = 0; r < 4; ++r) {
        int m = m0 + ty * 4 + r;
        float v[8];
#pragma unroll
        for (int c = 0; c < 8; ++c) v[c] = acc[r][c] + bs[c];
        float4 o = make_float4(fmaxf(v[0], v[1]), fmaxf(v[2], v[3]),
                               fmaxf(v[4], v[5]), fmaxf(v[6], v[7]));
        *(float4*)(gout + (size_t)m * 256 + (n0 >> 1) + tx * 4) = o;
    }
}

// ---------------- batched copy gate ----------------
__global__ __launch_bounds__(256) void k_copy(
    const float* __restrict__ h_hist, const float* __restrict__ ctx_hist,
    const float* __restrict__ W_copy, const float* __restrict__ b_copy,
    float* __restrict__ out)
{
    const int tid = threadIdx.x;
    const int lane = tid & 63;
    const int tb = blockIdx.x * 4 + (tid >> 6);
    const float* hp = h_hist + (size_t)tb * DD;
    const float* cp = ctx_hist + (size_t)tb * DD;
    float acc = 0.f;
#pragma unroll
    for (int j = 0; j < 8; ++j) {
        int k = lane + 64 * j;
        acc = fmaf(hp[k], W_copy[k], acc);
        acc = fmaf(cp[k], W_copy[512 + k], acc);
    }
#pragma unroll
    for (int off = 1; off < 64; off <<= 1) acc += __shfl_xor(acc, off);
    if (lane == 0) out[tb] = sigmf(acc + b_copy[0]);
}

// ---------------- tail outputs (hid, c_out[-1], cur_ctx) ----------------
__global__ void k_final(const float* __restrict__ h_hist,
                        const float* __restrict__ ctx_hist,
                        float* __restrict__ dout)
{
    int idx = blockIdx.x * 256 + threadIdx.x;
    if (idx < 32768) {
        dout[1050624 + idx] = h_hist[31 * 32768 + idx];
    } else if (idx < 49152) {
        int i2 = idx - 32768;
        dout[1083392 + i2] = dout[524288 + 507904 + i2];
    } else {
        int i2 = idx - 49152;
        dout[1099776 + i2] = ctx_hist[31 * 32768 + i2];
    }
}

extern "C" void kernel_launch(void* const* d_in, const int* in_sizes, int n_in,
                              void* d_out, int out_size, void* d_ws, size_t ws_size,
                              hipStream_t stream)
{
    (void)in_sizes; (void)n_in; (void)out_size; (void)ws_size;
    const int*   ids      = (const int*)d_in[0];
    const float* hidden   = (const float*)d_in[1];
    const float* context  = (const float*)d_in[2];
    const float* mask     = (const float*)d_in[3];
    const float* init_att = (const float*)d_in[4];
    const float* emb_t    = (const float*)d_in[5];
    const float* W_ih     = (const float*)d_in[6];
    const float* W_hh     = (const float*)d_in[7];
    const float* b_ih     = (const float*)d_in[8];
    const float* b_hh     = (const float*)d_in[9];
    const float* W_pre    = (const float*)d_in[10];
    const float* b_pre    = (const float*)d_in[11];
    const float* W_q      = (const float*)d_in[12];
    const float* v_att    = (const float*)d_in[13];
    const float* W_copy   = (const float*)d_in[14];
    const float* b_copy   = (const float*)d_in[15];
    const float* W_read   = (const float*)d_in[16];
    const float* b_read   = (const float*)d_in[17];
    float* out = (float*)d_out;
    float* ws = (float*)d_ws;

    float* pre      = ws;
    float* gxe      = ws + 8388608;
    float* h_hist   = ws + 11534336;
    float* ctx_hist = ws + 12582912;
    float* target   = ws + 13631488;
    float* energy   = ws + 13664256;
    float* cout     = out + 524288;

    // precompute[b][s][a] = ctx_t @ W_pre^T + b_pre
    gemm128<0><<<dim3(128, 4), 256, 0, stream>>>(context, W_pre, b_pre, pre, nullptr,
                                                 512, 512, 512);
    // gxe[t*64+b][j] = emb @ W_ih[:, :512]^T + b_ih
    gemm128<1><<<dim3(16, 12), 256, 0, stream>>>(emb_t, W_ih, b_ih, gxe, ids,
                                                 512, 1024, 1536);
    // fused 32-step recurrence (cooperative)
    {
        void* args[] = {
            (void*)&gxe, (void*)&hidden, (void*)&init_att,
            (void*)&W_ih, (void*)&W_hh, (void*)&b_hh, (void*)&W_q,
            (void*)&pre, (void*)&v_att, (void*)&mask, (void*)&context,
            (void*)&h_hist, (void*)&ctx_hist, (void*)&target, (void*)&energy,
            (void*)&cout
        };
        hipLaunchCooperativeKernel((void*)k_steps, dim3(128), dim3(256), args, 0,
                                   stream);
    }
    k_readout<<<dim3(32, 4), 256, 0, stream>>>(emb_t, ids, h_hist, ctx_hist,
                                               W_read, b_read, out);
    k_copy<<<512, 256, 0, stream>>>(h_hist, ctx_hist, W_copy, b_copy, out + 1048576);
    k_final<<<320, 256, 0, stream>>>(h_hist, ctx_hist, out);
}

// Round 3
// 1702.108 us; speedup vs baseline: 2.9271x; 2.9026x over previous
//
#include <hip/hip_runtime.h>
#include <hip/hip_bf16.h>

// Decoder: T=32, B=64, S=256, DEC=ENC=ATT=WV=512, V=32000, POOL=2
// Round 3: persistent cooperative kernel; pre+context bf16-resident in LDS
// (one (b, quarter) tile per block, 256 blocks = 1/CU); scoped atomic barriers
// (cluster=4 blocks per b, group=32 blocks per b%8) instead of grid.sync;
// GRU d-sliced per group with bf16-packed transposed weights.
//
// ws layout (float units):
//   preb     ushort[64][256][512] @ 0         (4194304 f)
//   gxe      f32  [2048][1536]    @ 4194304   (3145728)
//   h_hist   f32  [32][64][512]   @ 7340032   (1048576)
//   ctx_hist f32  [32][64][512]   @ 8388608   (1048576)
//   pe_buf   f32  [64][4][256]    @ 9437184   (65536)
//   WihcT_pk uint [256][1536]     @ 9502720   (393216)
//   WhhT_pk  uint [256][1536]     @ 9895936   (393216)
//   WqT_pk   uint [256][512]      @ 10289152  (131072)
//   counters uint [4096]          @ 10420224  (4096)   -> total 10424320 (41.7MB)

typedef unsigned int uint;
typedef unsigned short ushort;

#define DD 512
#define G3 1536

__device__ __forceinline__ float sigmf(float x) { return 1.0f / (1.0f + __expf(-x)); }
__device__ __forceinline__ float tanh_fast(float x) {
    float e = __expf(2.0f * x);
    return 1.0f - 2.0f / (e + 1.0f);
}
__device__ __forceinline__ ushort f2bf(float f) {
    uint b = __float_as_uint(f);
    return (ushort)((b + 0x7FFFu + ((b >> 16) & 1u)) >> 16);
}
__device__ __forceinline__ float bfl(uint u) { return __uint_as_float(u << 16); }
__device__ __forceinline__ float bfh(uint u) { return __uint_as_float(u & 0xFFFF0000u); }

// scoped barrier: one arrival per block on counter, wait until target arrivals
__device__ __forceinline__ void gbar(uint* c, uint target) {
    __syncthreads();
    if (threadIdx.x == 0) {
        __hip_atomic_fetch_add(c, 1u, __ATOMIC_RELEASE, __HIP_MEMORY_SCOPE_AGENT);
        while (__hip_atomic_load(c, __ATOMIC_ACQUIRE, __HIP_MEMORY_SCOPE_AGENT) < target)
            __builtin_amdgcn_s_sleep(2);
    }
    __syncthreads();
}

// ---------------- batched GEMM (f32 accum), two epilogues ----------------
// gemm_pre: C bf16 = context-rows @ W_pre^T + b_pre   (m = b*256+s)
__global__ __launch_bounds__(256) void gemm_pre(
    const float* __restrict__ A0, const float* __restrict__ Bm,
    const float* __restrict__ bias, ushort* __restrict__ C)
{
    __shared__ float As[16][132];
    __shared__ float Bs[16][132];
    const int tid = threadIdx.x;
    const int tx = tid & 15, ty = tid >> 4;
    const int m0 = blockIdx.x * 128, n0 = blockIdx.y * 128;
    float acc[8][8] = {};
    for (int k0 = 0; k0 < 512; k0 += 16) {
        __syncthreads();
#pragma unroll
        for (int qq = 0; qq < 2; ++qq) {
            int f = qq * 256 + tid;
            int row = f >> 2, kq = (f & 3) * 4;
            int m = m0 + row;
            int b = m >> 8, s = m & 255;
            const float* ap = A0 + (size_t)s * (64 * DD) + (size_t)b * DD + k0 + kq;
            float4 v = *(const float4*)ap;
            As[kq + 0][row] = v.x; As[kq + 1][row] = v.y;
            As[kq + 2][row] = v.z; As[kq + 3][row] = v.w;
            float4 w = *(const float4*)(Bm + (size_t)(n0 + row) * 512 + k0 + kq);
            Bs[kq + 0][row] = w.x; Bs[kq + 1][row] = w.y;
            Bs[kq + 2][row] = w.z; Bs[kq + 3][row] = w.w;
        }
        __syncthreads();
#pragma unroll
        for (int kk = 0; kk < 16; ++kk) {
            float4 a0 = *(const float4*)&As[kk][ty * 8];
            float4 a1 = *(const float4*)&As[kk][ty * 8 + 4];
            float4 b0 = *(const float4*)&Bs[kk][tx * 8];
            float4 b1 = *(const float4*)&Bs[kk][tx * 8 + 4];
            float ar[8] = {a0.x, a0.y, a0.z, a0.w, a1.x, a1.y, a1.z, a1.w};
            float br[8] = {b0.x, b0.y, b0.z, b0.w, b1.x, b1.y, b1.z, b1.w};
#pragma unroll
            for (int r = 0; r < 8; ++r)
#pragma unroll
                for (int cc = 0; cc < 8; ++cc)
                    acc[r][cc] = fmaf(ar[r], br[cc], acc[r][cc]);
        }
    }
    float bs[8];
#pragma unroll
    for (int cc = 0; cc < 8; ++cc) bs[cc] = bias[n0 + tx * 8 + cc];
#pragma unroll
    for (int r = 0; r < 8; ++r) {
        ushort* crow = C + (size_t)(m0 + ty * 8 + r) * 512 + n0 + tx * 8;
        uint4 o;
        o.x = (uint)f2bf(acc[r][0] + bs[0]) | ((uint)f2bf(acc[r][1] + bs[1]) << 16);
        o.y = (uint)f2bf(acc[r][2] + bs[2]) | ((uint)f2bf(acc[r][3] + bs[3]) << 16);
        o.z = (uint)f2bf(acc[r][4] + bs[4]) | ((uint)f2bf(acc[r][5] + bs[5]) << 16);
        o.w = (uint)f2bf(acc[r][6] + bs[6]) | ((uint)f2bf(acc[r][7] + bs[7]) << 16);
        *(uint4*)crow = o;
    }
}

// gemm_gxe: f32, A row m -> emb_table[ids[m]], B = W_ih (ldb 1024), out ldc 1536
__global__ __launch_bounds__(256) void gemm_gxe(
    const float* __restrict__ A0, const float* __restrict__ Bm,
    const float* __restrict__ bias, float* __restrict__ C,
    const int* __restrict__ ids)
{
    __shared__ float As[16][132];
    __shared__ float Bs[16][132];
    const int tid = threadIdx.x;
    const int tx = tid & 15, ty = tid >> 4;
    const int m0 = blockIdx.x * 128, n0 = blockIdx.y * 128;
    float acc[8][8] = {};
    for (int k0 = 0; k0 < 512; k0 += 16) {
        __syncthreads();
#pragma unroll
        for (int qq = 0; qq < 2; ++qq) {
            int f = qq * 256 + tid;
            int row = f >> 2, kq = (f & 3) * 4;
            const float* ap = A0 + (size_t)ids[m0 + row] * DD + k0 + kq;
            float4 v = *(const float4*)ap;
            As[kq + 0][row] = v.x; As[kq + 1][row] = v.y;
            As[kq + 2][row] = v.z; As[kq + 3][row] = v.w;
            float4 w = *(const float4*)(Bm + (size_t)(n0 + row) * 1024 + k0 + kq);
            Bs[kq + 0][row] = w.x; Bs[kq + 1][row] = w.y;
            Bs[kq + 2][row] = w.z; Bs[kq + 3][row] = w.w;
        }
        __syncthreads();
#pragma unroll
        for (int kk = 0; kk < 16; ++kk) {
            float4 a0 = *(const float4*)&As[kk][ty * 8];
            float4 a1 = *(const float4*)&As[kk][ty * 8 + 4];
            float4 b0 = *(const float4*)&Bs[kk][tx * 8];
            float4 b1 = *(const float4*)&Bs[kk][tx * 8 + 4];
            float ar[8] = {a0.x, a0.y, a0.z, a0.w, a1.x, a1.y, a1.z, a1.w};
            float br[8] = {b0.x, b0.y, b0.z, b0.w, b1.x, b1.y, b1.z, b1.w};
#pragma unroll
            for (int r = 0; r < 8; ++r)
#pragma unroll
                for (int cc = 0; cc < 8; ++cc)
                    acc[r][cc] = fmaf(ar[r], br[cc], acc[r][cc]);
        }
    }
    float bs[8];
#pragma unroll
    for (int cc = 0; cc < 8; ++cc) bs[cc] = bias[n0 + tx * 8 + cc];
#pragma unroll
    for (int r = 0; r < 8; ++r) {
        float* crow = C + (size_t)(m0 + ty * 8 + r) * 1536 + n0 + tx * 8;
        float4 o0 = make_float4(acc[r][0] + bs[0], acc[r][1] + bs[1],
                                acc[r][2] + bs[2], acc[r][3] + bs[3]);
        float4 o1 = make_float4(acc[r][4] + bs[4], acc[r][5] + bs[5],
                                acc[r][6] + bs[6], acc[r][7] + bs[7]);
        *(float4*)crow = o0;
        *(float4*)(crow + 4) = o1;
    }
}

// ---------------- weight transpose+pack prep ----------------
// WihcT[kp][row] packs W_ih[row][512+2kp | 512+2kp+1]; WhhT likewise from W_hh;
// WqT[kp][a] packs W_q[a][2kp | 2kp+1].
__global__ __launch_bounds__(512) void wprep(
    const float* __restrict__ W_ih, const float* __restrict__ W_hh,
    const float* __restrict__ W_q,
    uint* __restrict__ WihcT, uint* __restrict__ WhhT, uint* __restrict__ WqT)
{
    int id = blockIdx.x * 512 + threadIdx.x;
    if (id < 393216) {
        int kp = id / 1536, col = id - kp * 1536;
        float w0 = W_ih[(size_t)col * 1024 + 512 + 2 * kp];
        float w1 = W_ih[(size_t)col * 1024 + 512 + 2 * kp + 1];
        WihcT[id] = (uint)f2bf(w0) | ((uint)f2bf(w1) << 16);
    } else if (id < 786432) {
        int rid = id - 393216;
        int kp = rid / 1536, col = rid - kp * 1536;
        float w0 = W_hh[(size_t)col * 512 + 2 * kp];
        float w1 = W_hh[(size_t)col * 512 + 2 * kp + 1];
        WhhT[rid] = (uint)f2bf(w0) | ((uint)f2bf(w1) << 16);
    } else if (id < 917504) {
        int rid = id - 786432;
        int kp = rid >> 9, a = rid & 511;
        float w0 = W_q[(size_t)a * 512 + 2 * kp];
        float w1 = W_q[(size_t)a * 512 + 2 * kp + 1];
        WqT[rid] = (uint)f2bf(w0) | ((uint)f2bf(w1) << 16);
    }
}

// GRU partial-accumulate helper (static acc indices; inlined)
__device__ __forceinline__ void gru_acc(const float* __restrict__ sx,
                                        const uint* __restrict__ wbase,
                                        int h2, int bi, float (&acc)[3])
{
#pragma unroll 8
    for (int kk = 0; kk < 32; ++kk) {
        int kp_l = h2 * 32 + kk;
        float xv0 = sx[kp_l * 16 + bi * 2 + 0];
        float xv1 = sx[kp_l * 16 + bi * 2 + 1];
        const uint* wr = wbase + (size_t)kp_l * 1536;
        uint w0 = wr[0], w1 = wr[512], w2 = wr[1024];
        acc[0] = fmaf(bfl(w0), xv0, fmaf(bfh(w0), xv1, acc[0]));
        acc[1] = fmaf(bfl(w1), xv0, fmaf(bfh(w1), xv1, acc[1]));
        acc[2] = fmaf(bfl(w2), xv0, fmaf(bfh(w2), xv1, acc[2]));
    }
}

// ---------------- persistent 32-step kernel ----------------
// 256 blocks x 512 threads, 1/CU. block: q = blk>>6 (quarter), b = blk&63.
// group = blocks with same b%8 (32 blocks, same XCD by blk%8); cluster = 4 q's of b.
__global__ __launch_bounds__(512, 1) void k_steps(
    const float* __restrict__ gxe, const float* __restrict__ hidden,
    const float* __restrict__ init_att, const float* __restrict__ context,
    const float* __restrict__ mask, const float* __restrict__ v_att,
    const float* __restrict__ b_hh, const ushort* __restrict__ preb,
    const uint* __restrict__ WihcT, const uint* __restrict__ WhhT,
    const uint* __restrict__ WqT,
    float* __restrict__ h_hist, float* __restrict__ ctx_hist,
    float* __restrict__ pe_buf, uint* __restrict__ cnt,
    float* __restrict__ cout)
{
    __shared__ ushort preT[256 * 128];   // [s][a-slice], XOR-swizzled 16B chunks
    __shared__ ushort ctxT[256 * 128];   // [s][e-slice], linear
    __shared__ float smask[256];
    __shared__ float svatt[128];
    __shared__ float scratch[3072];

    const int tid = threadIdx.x;
    const int blk = blockIdx.x;
    const int q = blk >> 6;
    const int b = blk & 63;
    const int r = b & 7;
    const int u = ((b >> 3) << 2) | q;   // group-local d-slice id [0,32)

    uint* cl_cnt = cnt + b * 32;
    uint* gr_cnt = cnt + 2048 + r * 32;

    // ---- one-time staging: pre(bf16) + context(->bf16) into LDS ----
#pragma unroll
    for (int cc = 0; cc < 8; ++cc) {
        int cid = tid * 8 + cc;
        int s = cid >> 4, ch = cid & 15;
        int sw = (s ^ (s >> 3)) & 7;
        uint4 pv = *(const uint4*)(preb + ((size_t)(b * 256 + s)) * 512 + q * 128 + ch * 8);
        *(uint4*)&preT[s * 128 + ((ch ^ sw) << 3)] = pv;
        const float* cp = context + ((size_t)s * 64 + b) * 512 + q * 128 + ch * 8;
        float4 c0 = *(const float4*)cp;
        float4 c1 = *(const float4*)(cp + 4);
        uint4 cv;
        cv.x = (uint)f2bf(c0.x) | ((uint)f2bf(c0.y) << 16);
        cv.y = (uint)f2bf(c0.z) | ((uint)f2bf(c0.w) << 16);
        cv.z = (uint)f2bf(c1.x) | ((uint)f2bf(c1.y) << 16);
        cv.w = (uint)f2bf(c1.z) | ((uint)f2bf(c1.w) << 16);
        *(uint4*)&ctxT[s * 128 + ch * 8] = cv;
    }
    if (tid < 256) smask[tid] = mask[b * 256 + tid];
    if (tid < 128) svatt[tid] = v_att[q * 128 + tid];

    const int j = tid & 15;
    const int bi = (tid >> 4) & 7;
    const int h2 = tid >> 7;

    for (int t = 0; t < 32; ++t) {
        const float* ctxp = t ? (ctx_hist + (size_t)(t - 1) * 32768) : init_att;
        const float* hp = t ? (h_hist + (size_t)(t - 1) * 32768) : hidden;

        // ---- P1: GRU, d-slice [u*16,u*16+16) for the group's 8 b's ----
        float ax[3] = {0.f, 0.f, 0.f}, ah[3] = {0.f, 0.f, 0.f};
#pragma unroll
        for (int c = 0; c < 4; ++c) {
            const float* xsrc = (c < 2) ? ctxp : hp;
            const uint* WT = (c < 2) ? WihcT : WhhT;
            int cb = (c & 1) * 256;
            __syncthreads();
            {
                int bi_s = tid >> 6;
                int k4 = (tid & 63) * 4;
                float4 v = *(const float4*)(xsrc + (size_t)(r + bi_s * 8) * 512 + cb + k4);
                int kp2 = (tid & 63) * 2;
                scratch[kp2 * 16 + bi_s * 2 + 0] = v.x;
                scratch[kp2 * 16 + bi_s * 2 + 1] = v.y;
                scratch[kp2 * 16 + 16 + bi_s * 2 + 0] = v.z;
                scratch[kp2 * 16 + 16 + bi_s * 2 + 1] = v.w;
            }
            __syncthreads();
            const uint* wbase = WT + (size_t)((c & 1) * 128) * 1536 + u * 16 + j;
            if (c < 2) gru_acc(scratch, wbase, h2, bi, ax);
            else       gru_acc(scratch, wbase, h2, bi, ah);
        }
        __syncthreads();
#pragma unroll
        for (int g = 0; g < 3; ++g) {
            scratch[(g * 2 + 0) * 512 + h2 * 128 + bi * 16 + j] = ax[g];
            scratch[(g * 2 + 1) * 512 + h2 * 128 + bi * 16 + j] = ah[g];
        }
        __syncthreads();
        if (tid < 128) {
            int jj = tid & 15, bi2 = tid >> 4;
            int bb = r + bi2 * 8;
            int d = u * 16 + jj;
            float AX[3], AH[3];
#pragma unroll
            for (int g = 0; g < 3; ++g) {
                float sx = 0.f, sh = 0.f;
#pragma unroll
                for (int h = 0; h < 4; ++h) {
                    sx += scratch[(g * 2 + 0) * 512 + h * 128 + bi2 * 16 + jj];
                    sh += scratch[(g * 2 + 1) * 512 + h * 128 + bi2 * 16 + jj];
                }
                AX[g] = sx + gxe[((size_t)t * 64 + bb) * 1536 + g * 512 + d];
                AH[g] = sh + b_hh[g * 512 + d];
            }
            float rr = sigmf(AX[0] + AH[0]);
            float zz = sigmf(AX[1] + AH[1]);
            float nn = tanh_fast(AX[2] + rr * AH[2]);
            float hpv = hp[(size_t)bb * 512 + d];
            h_hist[(size_t)t * 32768 + (size_t)bb * 512 + d] = (1.0f - zz) * nn + zz * hpv;
        }
        gbar(gr_cnt, (uint)(64 * t + 32));

        // ---- P2: target a-slice from full h[b] ----
        {
            const float* h_cur = h_hist + (size_t)t * 32768 + (size_t)b * 512;
            scratch[tid] = h_cur[tid];
        }
        __syncthreads();
        {
            int a = tid & 127, dq = tid >> 7;
            const uint* wq = WqT + (size_t)(dq * 64) * 512 + q * 128 + a;
            float acc = 0.f;
#pragma unroll 8
            for (int i = 0; i < 64; ++i) {
                uint w = wq[(size_t)i * 512];
                float hv0 = scratch[(dq * 64 + i) * 2 + 0];
                float hv1 = scratch[(dq * 64 + i) * 2 + 1];
                acc = fmaf(bfl(w), hv0, fmaf(bfh(w), hv1, acc));
            }
            scratch[512 + tid] = acc;
        }
        __syncthreads();
        if (tid < 128)
            scratch[1024 + tid] = scratch[512 + tid] + scratch[640 + tid] +
                                  scratch[768 + tid] + scratch[896 + tid];
        __syncthreads();

        // ---- P3: partial energy over a-slice, all 256 s ----
        {
            int s = tid & 255, hf = tid >> 8;
            int sw = (s ^ (s >> 3)) & 7;
            float acc = 0.f;
#pragma unroll
            for (int c8 = 0; c8 < 8; ++c8) {
                int ch = hf * 8 + c8;
                uint4 pv = *(const uint4*)&preT[s * 128 + ((ch ^ sw) << 3)];
                int ab = ch * 8;
                acc += svatt[ab + 0] * tanh_fast(bfl(pv.x) + scratch[1024 + ab + 0]);
                acc += svatt[ab + 1] * tanh_fast(bfh(pv.x) + scratch[1024 + ab + 1]);
                acc += svatt[ab + 2] * tanh_fast(bfl(pv.y) + scratch[1024 + ab + 2]);
                acc += svatt[ab + 3] * tanh_fast(bfh(pv.y) + scratch[1024 + ab + 3]);
                acc += svatt[ab + 4] * tanh_fast(bfl(pv.z) + scratch[1024 + ab + 4]);
                acc += svatt[ab + 5] * tanh_fast(bfh(pv.z) + scratch[1024 + ab + 5]);
                acc += svatt[ab + 6] * tanh_fast(bfl(pv.w) + scratch[1024 + ab + 6]);
                acc += svatt[ab + 7] * tanh_fast(bfh(pv.w) + scratch[1024 + ab + 7]);
            }
            scratch[1280 + tid] = acc;
        }
        __syncthreads();
        if (tid < 256)
            pe_buf[(size_t)b * 1024 + q * 256 + tid] =
                scratch[1280 + tid] + scratch[1536 + tid];
        gbar(cl_cnt, (uint)(4 * t + 4));

        // ---- P4: softmax (redundant per block) + ctx GEMV e-slice ----
        {
            int s2 = tid & 255;
            const float* peb = pe_buf + (size_t)b * 1024;
            float e = peb[s2] + peb[256 + s2] + peb[512 + s2] + peb[768 + s2];
            float mk = smask[s2];
            e = e * (1.0f - mk) + mk * (-1e6f);
            float mx = e;
#pragma unroll
            for (int off = 1; off < 64; off <<= 1) mx = fmaxf(mx, __shfl_xor(mx, off));
            int wv = tid >> 6;
            if ((tid & 63) == 0) scratch[2560 + wv] = mx;
            __syncthreads();
            mx = scratch[2560];
#pragma unroll
            for (int w = 1; w < 8; ++w) mx = fmaxf(mx, scratch[2560 + w]);
            float ex = __expf(e - mx);
            float sm = ex;
#pragma unroll
            for (int off = 1; off < 64; off <<= 1) sm += __shfl_xor(sm, off);
            if ((tid & 63) == 0) scratch[2568 + wv] = sm;
            __syncthreads();
            sm = scratch[2568] + scratch[2569] + scratch[2570] + scratch[2571];
            float sc = ex / sm;
            scratch[1792 + s2] = sc;
            if (q == 0 && tid < 256) cout[((size_t)t * 64 + b) * 256 + tid] = sc;
        }
        __syncthreads();
        {
            int e_l = tid & 127, sq = tid >> 7;
            float acc = 0.f;
#pragma unroll 8
            for (int i = 0; i < 64; ++i) {
                int s = sq * 64 + i;
                float cv = __uint_as_float(((uint)ctxT[s * 128 + e_l]) << 16);
                acc = fmaf(scratch[1792 + s], cv, acc);
            }
            scratch[2048 + tid] = acc;
        }
        __syncthreads();
        if (tid < 128) {
            float val = scratch[2048 + tid] + scratch[2176 + tid] +
                        scratch[2304 + tid] + scratch[2432 + tid];
            ctx_hist[(size_t)t * 32768 + (size_t)b * 512 + q * 128 + tid] = val;
        }
        gbar(gr_cnt, (uint)(64 * t + 64));
    }
}

// ---------------- batched readout + maxout (64x64 tiles, 256 blocks) ----------------
__global__ __launch_bounds__(256) void k_readout(
    const float* __restrict__ emb_table, const int* __restrict__ ids,
    const float* __restrict__ h_hist, const float* __restrict__ ctx_hist,
    const float* __restrict__ W_read, const float* __restrict__ b_read,
    float* __restrict__ gout)
{
    __shared__ float As[16][68];
    __shared__ float Bs[16][68];
    const int tid = threadIdx.x;
    const int tx = tid & 15, ty = tid >> 4;
    const int m0 = blockIdx.x * 64, n0 = blockIdx.y * 64;
    float acc[4][4] = {};
    for (int k0 = 0; k0 < G3; k0 += 16) {
        __syncthreads();
        {
            int row = tid >> 2, kq = (tid & 3) * 4;
            int m = m0 + row, k = k0 + kq;
            const float* ap;
            if (k < 512)       ap = emb_table + (size_t)ids[m] * DD + k;
            else if (k < 1024) ap = h_hist + (size_t)m * DD + (k - 512);
            else               ap = ctx_hist + (size_t)m * DD + (k - 1024);
            float4 v = *(const float4*)ap;
            As[kq + 0][row] = v.x; As[kq + 1][row] = v.y;
            As[kq + 2][row] = v.z; As[kq + 3][row] = v.w;
            float4 w = *(const float4*)(W_read + (size_t)(n0 + row) * G3 + k0 + kq);
            Bs[kq + 0][row] = w.x; Bs[kq + 1][row] = w.y;
            Bs[kq + 2][row] = w.z; Bs[kq + 3][row] = w.w;
        }
        __syncthreads();
#pragma unroll
        for (int kk = 0; kk < 16; ++kk) {
            float4 a = *(const float4*)&As[kk][ty * 4];
            float4 bb = *(const float4*)&Bs[kk][tx * 4];
            float ar[4] = {a.x, a.y, a.z, a.w};
            float br[4] = {bb.x, bb.y, bb.z, bb.w};
#pragma unroll
            for (int r = 0; r < 4; ++r)
#pragma unroll
                for (int c = 0; c < 4; ++c)
                    acc[r][c] = fmaf(ar[r], br[c], acc[r][c]);
        }
    }
    float bs[4];
#pragma unroll
    for (int c = 0; c < 4; ++c) bs[c] = b_read[n0 + tx * 4 + c];
#pragma unroll
    for (int r = 0; r < 4; ++r) {
        int m = m0 + ty * 4 + r;
        float v0 = acc[r][0] + bs[0], v1 = acc[r][1] + bs[1];
        float v2 = acc[r][2] + bs[2], v3 = acc[r][3] + bs[3];
        float2 o = make_float2(fmaxf(v0, v1), fmaxf(v2, v3));
        *(float2*)(gout + (size_t)m * 256 + (n0 >> 1) + tx * 2) = o;
    }
}

// ---------------- batched copy gate ----------------
__global__ __launch_bounds__(256) void k_copy(
    const float* __restrict__ h_hist, const float* __restrict__ ctx_hist,
    const float* __restrict__ W_copy, const float* __restrict__ b_copy,
    float* __restrict__ out)
{
    const int tid = threadIdx.x;
    const int lane = tid & 63;
    const int tb = blockIdx.x * 4 + (tid >> 6);
    const float* hp = h_hist + (size_t)tb * DD;
    const float* cp = ctx_hist + (size_t)tb * DD;
    float acc = 0.f;
#pragma unroll
    for (int jj = 0; jj < 8; ++jj) {
        int k = lane + 64 * jj;
        acc = fmaf(hp[k], W_copy[k], acc);
        acc = fmaf(cp[k], W_copy[512 + k], acc);
    }
#pragma unroll
    for (int off = 1; off < 64; off <<= 1) acc += __shfl_xor(acc, off);
    if (lane == 0) out[tb] = sigmf(acc + b_copy[0]);
}

// ---------------- tail outputs ----------------
__global__ void k_final(const float* __restrict__ h_hist,
                        const float* __restrict__ ctx_hist,
                        float* __restrict__ dout)
{
    int idx = blockIdx.x * 256 + threadIdx.x;
    if (idx < 32768) {
        dout[1050624 + idx] = h_hist[31 * 32768 + idx];
    } else if (idx < 49152) {
        int i2 = idx - 32768;
        dout[1083392 + i2] = dout[524288 + 507904 + i2];
    } else {
        int i2 = idx - 49152;
        dout[1099776 + i2] = ctx_hist[31 * 32768 + i2];
    }
}

extern "C" void kernel_launch(void* const* d_in, const int* in_sizes, int n_in,
                              void* d_out, int out_size, void* d_ws, size_t ws_size,
                              hipStream_t stream)
{
    (void)in_sizes; (void)n_in; (void)out_size; (void)ws_size;
    const int*   ids      = (const int*)d_in[0];
    const float* hidden   = (const float*)d_in[1];
    const float* context  = (const float*)d_in[2];
    const float* mask     = (const float*)d_in[3];
    const float* init_att = (const float*)d_in[4];
    const float* emb_t    = (const float*)d_in[5];
    const float* W_ih     = (const float*)d_in[6];
    const float* W_hh     = (const float*)d_in[7];
    const float* b_ih     = (const float*)d_in[8];
    const float* b_hh     = (const float*)d_in[9];
    const float* W_pre    = (const float*)d_in[10];
    const float* b_pre    = (const float*)d_in[11];
    const float* W_q      = (const float*)d_in[12];
    const float* v_att    = (const float*)d_in[13];
    const float* W_copy   = (const float*)d_in[14];
    const float* b_copy   = (const float*)d_in[15];
    const float* W_read   = (const float*)d_in[16];
    const float* b_read   = (const float*)d_in[17];
    float* out = (float*)d_out;
    float* ws = (float*)d_ws;

    ushort* preb    = (ushort*)ws;
    float* gxe      = ws + 4194304;
    float* h_hist   = ws + 7340032;
    float* ctx_hist = ws + 8388608;
    float* pe_buf   = ws + 9437184;
    uint* WihcT     = (uint*)(ws + 9502720);
    uint* WhhT      = (uint*)(ws + 9895936);
    uint* WqT       = (uint*)(ws + 10289152);
    uint* cnt       = (uint*)(ws + 10420224);
    float* cout     = out + 524288;

    hipMemsetAsync(cnt, 0, 16384, stream);
    gemm_pre<<<dim3(128, 4), 256, 0, stream>>>(context, W_pre, b_pre, preb);
    gemm_gxe<<<dim3(16, 12), 256, 0, stream>>>(emb_t, W_ih, b_ih, gxe, ids);
    wprep<<<1792, 512, 0, stream>>>(W_ih, W_hh, W_q, WihcT, WhhT, WqT);
    {
        void* args[] = {
            (void*)&gxe, (void*)&hidden, (void*)&init_att, (void*)&context,
            (void*)&mask, (void*)&v_att, (void*)&b_hh, (void*)&preb,
            (void*)&WihcT, (void*)&WhhT, (void*)&WqT,
            (void*)&h_hist, (void*)&ctx_hist, (void*)&pe_buf, (void*)&cnt,
            (void*)&cout
        };
        hipLaunchCooperativeKernel((void*)k_steps, dim3(256), dim3(512), args, 0,
                                   stream);
    }
    k_readout<<<dim3(32, 8), 256, 0, stream>>>(emb_t, ids, h_hist, ctx_hist,
                                               W_read, b_read, out);
    k_copy<<<512, 256, 0, stream>>>(h_hist, ctx_hist, W_copy, b_copy, out + 1048576);
    k_final<<<320, 256, 0, stream>>>(h_hist, ctx_hist, out);
}

// Round 4
// 1179.695 us; speedup vs baseline: 4.2234x; 1.4428x over previous
//
#include <hip/hip_runtime.h>
#include <hip/hip_bf16.h>

// Decoder: T=32, B=64, S=256, DEC=ENC=ATT=WV=512, V=32000, POOL=2
// Round 4: MFMA everywhere. k_steps P1 (GRU) uses mfma_f32_16x16x32_bf16 with
// weights pre-packed in B-fragment order (1KB coalesced per MFMA); batched
// GEMMs (pre/gxe/readout) share one MFMA template. LDS: preT 64K + ctxT 64K +
// 24K multiplexed scratch = 152KB, 1 block/CU.
//
// ws layout (float units):
//   preb     ushort[64][256][512] @ 0         (4194304 f)
//   gxe      f32  [2048][1536]    @ 4194304   (3145728)
//   h_hist   f32  [32][64][512]   @ 7340032   (1048576)
//   ctx_hist f32  [32][64][512]   @ 8388608   (1048576)
//   pe_buf   f32  [64][4][256]    @ 9437184   (65536)
//   Wpk      uint [786432]        @ 9502720   (786432)   GRU weights, B-frag order
//   WqT      uint [256][512]      @ 10289152  (131072)
//   counters uint [4096]          @ 10420224  (4096)

typedef unsigned int uint;
typedef unsigned short ushort;
typedef __attribute__((ext_vector_type(8))) short s8v;   // 8 bf16
typedef __attribute__((ext_vector_type(4))) float f4v;   // 4 f32

#define DD 512

__device__ __forceinline__ float sigmf(float x) { return 1.0f / (1.0f + __expf(-x)); }
__device__ __forceinline__ float tanh_fast(float x) {
    float e = __expf(2.0f * x);
    return 1.0f - 2.0f / (e + 1.0f);
}
__device__ __forceinline__ ushort f2bf(float f) {
    uint b = __float_as_uint(f);
    return (ushort)((b + 0x7FFFu + ((b >> 16) & 1u)) >> 16);
}
__device__ __forceinline__ uint pk2(float a, float b) {
    return (uint)f2bf(a) | ((uint)f2bf(b) << 16);
}
__device__ __forceinline__ float bfl(uint u) { return __uint_as_float(u << 16); }
__device__ __forceinline__ float bfh(uint u) { return __uint_as_float(u & 0xFFFF0000u); }
__device__ __forceinline__ f4v MFMA(s8v a, s8v b, f4v c) {
    return __builtin_amdgcn_mfma_f32_16x16x32_bf16(a, b, c, 0, 0, 0);
}

__device__ __forceinline__ void gbar(uint* c, uint target) {
    __syncthreads();
    if (threadIdx.x == 0) {
        __hip_atomic_fetch_add(c, 1u, __ATOMIC_RELEASE, __HIP_MEMORY_SCOPE_AGENT);
        while (__hip_atomic_load(c, __ATOMIC_ACQUIRE, __HIP_MEMORY_SCOPE_AGENT) < target)
            __builtin_amdgcn_s_sleep(2);
    }
    __syncthreads();
}

// ================= unified MFMA GEMM: C[M,N] = A[M,K] @ B[N,K]^T + bias =======
// MODE 0 (PRE):  A row m -> context[m&255][m>>8][:], out bf16 ldc 512
// MODE 1 (GXE):  A row m -> emb_table[ids[m]][:],    out f32 ldc 1536
// MODE 2 (READ): A row m -> concat(emb|h_hist|ctx_hist), maxout f32 out ldc 256
// BM=BN=64, 256 threads (4 waves), K-chunks of 32.
template <int MODE>
__global__ __launch_bounds__(256) void mgemm(
    const float* __restrict__ A0, const float* __restrict__ A1,
    const float* __restrict__ A2, const int* __restrict__ ids,
    const float* __restrict__ Bm, const float* __restrict__ bias,
    void* __restrict__ Cout, int ldb, int K)
{
    __shared__ __align__(16) ushort Ab[64 * 32];
    __shared__ __align__(16) ushort Bb[64 * 32];
    __shared__ int rid[64];
    const int tid = threadIdx.x;
    const int m0 = blockIdx.x * 64, n0 = blockIdx.y * 64;
    if (MODE != 0 && tid < 64) rid[tid] = ids[m0 + tid];
    const int lane = tid & 63;
    const int w = tid >> 6;
    const int srow = tid >> 2, sc = tid & 3;
    f4v acc[4];
#pragma unroll
    for (int mt = 0; mt < 4; ++mt) acc[mt] = (f4v){0.f, 0.f, 0.f, 0.f};

    for (int k0 = 0; k0 < K; k0 += 32) {
        __syncthreads();
        {
            const float* ap;
            int m = m0 + srow;
            if (MODE == 0) {
                ap = A0 + (size_t)(m & 255) * 32768 + (size_t)(m >> 8) * 512 + k0 + sc * 8;
            } else if (MODE == 1) {
                ap = A0 + (size_t)rid[srow] * 512 + k0 + sc * 8;
            } else {
                if (k0 < 512)       ap = A0 + (size_t)rid[srow] * 512 + k0 + sc * 8;
                else if (k0 < 1024) ap = A1 + (size_t)m * 512 + (k0 - 512) + sc * 8;
                else                ap = A2 + (size_t)m * 512 + (k0 - 1024) + sc * 8;
            }
            float4 v0 = *(const float4*)ap;
            float4 v1 = *(const float4*)(ap + 4);
            uint4 pa;
            pa.x = pk2(v0.x, v0.y); pa.y = pk2(v0.z, v0.w);
            pa.z = pk2(v1.x, v1.y); pa.w = pk2(v1.z, v1.w);
            *(uint4*)&Ab[srow * 32 + ((sc ^ (srow & 3)) << 3)] = pa;
            const float* bp = Bm + (size_t)(n0 + srow) * ldb + k0 + sc * 8;
            float4 w0 = *(const float4*)bp;
            float4 w1 = *(const float4*)(bp + 4);
            uint4 pb;
            pb.x = pk2(w0.x, w0.y); pb.y = pk2(w0.z, w0.w);
            pb.z = pk2(w1.x, w1.y); pb.w = pk2(w1.z, w1.w);
            *(uint4*)&Bb[srow * 32 + ((sc ^ (srow & 3)) << 3)] = pb;
        }
        __syncthreads();
        int rr = lane & 15, kc = lane >> 4;
        s8v bf = *(const s8v*)&Bb[(w * 16 + rr) * 32 + ((kc ^ (rr & 3)) << 3)];
#pragma unroll
        for (int mt = 0; mt < 4; ++mt) {
            s8v af = *(const s8v*)&Ab[(mt * 16 + rr) * 32 + ((kc ^ (rr & 3)) << 3)];
            acc[mt] = MFMA(af, bf, acc[mt]);
        }
    }
    float bv = bias[n0 + w * 16 + (lane & 15)];
#pragma unroll
    for (int mt = 0; mt < 4; ++mt) {
#pragma unroll
        for (int r2 = 0; r2 < 4; ++r2) {
            int m = m0 + mt * 16 + (lane >> 4) * 4 + r2;
            int n = n0 + w * 16 + (lane & 15);
            float v = acc[mt][r2] + bv;
            if (MODE == 0) {
                ((ushort*)Cout)[(size_t)m * 512 + n] = f2bf(v);
            } else if (MODE == 1) {
                ((float*)Cout)[(size_t)m * 1536 + n] = v;
            } else {
                float vm = fmaxf(v, __shfl_xor(v, 1));
                if (!(lane & 1)) ((float*)Cout)[(size_t)m * 256 + (n >> 1)] = vm;
            }
        }
    }
}

// ================= weight prep: Wpk (B-fragment order) + WqT ==================
// Wpk chunk (u,mat,ks,g): uint idx = (((u*2+mat)*16+ks)*3+g)*256 + lane*4 + e2
//   value pair: W[n][k],W[n][k+1]; n = g*512+u*16+(lane&15); k = ks*32+(lane>>4)*8+e2*2
//   mat0: W_ih[n][512+k] (ctx part), mat1: W_hh[n][k]
__global__ __launch_bounds__(512) void wprep2(
    const float* __restrict__ W_ih, const float* __restrict__ W_hh,
    const float* __restrict__ W_q,
    uint* __restrict__ Wpk, uint* __restrict__ WqT)
{
    int id = blockIdx.x * 512 + threadIdx.x;
    if (id < 786432) {
        int l4 = id & 255;
        int chunk = id >> 8;
        int g = chunk % 3;
        int t2 = chunk / 3;
        int ks = t2 & 15;
        int mat = (t2 >> 4) & 1;
        int u = t2 >> 5;
        int lane = l4 >> 2, e2 = l4 & 3;
        int n = g * 512 + u * 16 + (lane & 15);
        int k = ks * 32 + ((lane >> 4) << 3) + e2 * 2;
        float w0, w1;
        if (mat == 0) {
            w0 = W_ih[(size_t)n * 1024 + 512 + k];
            w1 = W_ih[(size_t)n * 1024 + 512 + k + 1];
        } else {
            w0 = W_hh[(size_t)n * 512 + k];
            w1 = W_hh[(size_t)n * 512 + k + 1];
        }
        Wpk[id] = pk2(w0, w1);
    } else if (id < 917504) {
        int rid2 = id - 786432;
        int kp = rid2 >> 9, a = rid2 & 511;
        WqT[rid2] = pk2(W_q[(size_t)a * 512 + 2 * kp], W_q[(size_t)a * 512 + 2 * kp + 1]);
    }
}

// ================= persistent 32-step kernel ==================================
// 256 blocks x 512 thr (8 waves), 1/CU. q = blk>>6, b = blk&63, r = b&7,
// u = ((b>>3)<<2)|q  (group-local d-slice, group = 32 blocks same r, same XCD).
__global__ __launch_bounds__(512, 1) void k_steps(
    const float* __restrict__ gxe, const float* __restrict__ hidden,
    const float* __restrict__ init_att, const float* __restrict__ context,
    const float* __restrict__ mask, const float* __restrict__ v_att,
    const float* __restrict__ b_hh, const ushort* __restrict__ preb,
    const uint* __restrict__ Wpk, const uint* __restrict__ WqT,
    float* __restrict__ h_hist, float* __restrict__ ctx_hist,
    float* __restrict__ pe_buf, uint* __restrict__ cnt,
    float* __restrict__ cout)
{
    __shared__ __align__(16) ushort preT[256 * 128];   // [s][a-slice], swizzled
    __shared__ __align__(16) ushort ctxT[256 * 128];   // [s][e-slice], linear
    __shared__ __align__(16) float scrF[6144];         // 24KB multiplexed

    const int tid = threadIdx.x;
    const int blk = blockIdx.x;
    const int q = blk >> 6;
    const int b = blk & 63;
    const int r = b & 7;
    const int u = ((b >> 3) << 2) | q;
    const int lane = tid & 63;
    const int wid = __builtin_amdgcn_readfirstlane(tid >> 6);

    uint* cl_cnt = cnt + b * 32;
    uint* gr_cnt = cnt + 2048 + r * 32;

    // ---- one-time staging: pre(bf16) + context(->bf16) into LDS ----
#pragma unroll
    for (int cc = 0; cc < 8; ++cc) {
        int cid = tid * 8 + cc;
        int s = cid >> 4, ch = cid & 15;
        int sw = (s ^ (s >> 3)) & 7;
        uint4 pv = *(const uint4*)(preb + ((size_t)(b * 256 + s)) * 512 + q * 128 + ch * 8);
        *(uint4*)&preT[s * 128 + ((ch ^ sw) << 3)] = pv;
        const float* cp = context + ((size_t)s * 64 + b) * 512 + q * 128 + ch * 8;
        float4 c0 = *(const float4*)cp;
        float4 c1 = *(const float4*)(cp + 4);
        uint4 cv;
        cv.x = pk2(c0.x, c0.y); cv.y = pk2(c0.z, c0.w);
        cv.z = pk2(c1.x, c1.y); cv.w = pk2(c1.z, c1.w);
        *(uint4*)&ctxT[s * 128 + ch * 8] = cv;
    }

    const int mat_w = wid >> 2, kw = wid & 3;   // wave role in P1

    for (int t = 0; t < 32; ++t) {
        const float* ctxp = t ? (ctx_hist + (size_t)(t - 1) * 32768) : init_att;
        const float* hp = t ? (h_hist + (size_t)(t - 1) * 32768) : hidden;

        // ---- P1a: stage x (ctx_prev, h_prev for group's 8 b's) -> LDS bf16 ----
        __syncthreads();
        {
            int c2 = tid & 31, row = (tid >> 5) & 7, mat = tid >> 8;
            const float* src = mat ? hp : ctxp;
            int bb = r + row * 8;
            const float* sp = src + (size_t)bb * 512 + c2 * 16;
            float4 v0 = *(const float4*)sp, v1 = *(const float4*)(sp + 4);
            float4 v2 = *(const float4*)(sp + 8), v3 = *(const float4*)(sp + 12);
            uint4 p0, p1;
            p0.x = pk2(v0.x, v0.y); p0.y = pk2(v0.z, v0.w);
            p0.z = pk2(v1.x, v1.y); p0.w = pk2(v1.z, v1.w);
            p1.x = pk2(v2.x, v2.y); p1.y = pk2(v2.z, v2.w);
            p1.z = pk2(v3.x, v3.y); p1.w = pk2(v3.z, v3.w);
            char* xb = (char*)scrF + mat * 8192 + row * 1024;
            int c0 = c2 * 2;
            *(uint4*)(xb + ((c0 ^ row) << 4)) = p0;
            *(uint4*)(xb + (((c0 + 1) ^ row) << 4)) = p1;
        }
        __syncthreads();
        // ---- P1b: MFMA  (wave: mat=wid>>2, K-slice kw*128) ----
        f4v ac0 = (f4v){0.f, 0.f, 0.f, 0.f};
        f4v ac1 = ac0, ac2 = ac0;
        {
            const char* xbase = (const char*)scrF + mat_w * 8192 + (lane & 15) * 1024;
            int rsw = (lane & 15) & 7;
#pragma unroll
            for (int s = 0; s < 4; ++s) {
                int ch = kw * 16 + s * 4 + (lane >> 4);
                s8v af = *(const s8v*)(xbase + ((ch ^ rsw) << 4));
                int ks = kw * 4 + s;
                const uint* wb = Wpk + ((((u * 2 + mat_w) * 16 + ks) * 3) << 8) + (lane << 2);
                s8v b0 = *(const s8v*)(wb);
                s8v b1 = *(const s8v*)(wb + 256);
                s8v b2 = *(const s8v*)(wb + 512);
                ac0 = MFMA(af, b0, ac0);
                ac1 = MFMA(af, b1, ac1);
                ac2 = MFMA(af, b2, ac2);
            }
        }
        __syncthreads();
        {
            f4v* rb = (f4v*)scrF;
            rb[((mat_w * 3 + 0) * 4 + kw) * 64 + lane] = ac0;
            rb[((mat_w * 3 + 1) * 4 + kw) * 64 + lane] = ac1;
            rb[((mat_w * 3 + 2) * 4 + kw) * 64 + lane] = ac2;
        }
        __syncthreads();
        // ---- P1c: reduce + gates (128 threads: 8 b x 16 d) ----
        if (tid < 128) {
            int bloc = tid >> 4, jj = tid & 15;
            int bb = r + bloc * 8;
            int d = u * 16 + jj;
            int eidx = ((jj + ((bloc >> 2) << 4)) << 2) + (bloc & 3);
            float AX[3], AH[3];
#pragma unroll
            for (int g = 0; g < 3; ++g) {
                float sx = 0.f, sh = 0.f;
#pragma unroll
                for (int kw2 = 0; kw2 < 4; ++kw2) {
                    sx += scrF[((0 + g) * 4 + kw2) * 256 + eidx];
                    sh += scrF[((3 + g) * 4 + kw2) * 256 + eidx];
                }
                AX[g] = sx + gxe[((size_t)t * 64 + bb) * 1536 + g * 512 + d];
                AH[g] = sh + b_hh[g * 512 + d];
            }
            float rr = sigmf(AX[0] + AH[0]);
            float zz = sigmf(AX[1] + AH[1]);
            float nn = tanh_fast(AX[2] + rr * AH[2]);
            float hpv = hp[(size_t)bb * 512 + d];
            h_hist[(size_t)t * 32768 + (size_t)bb * 512 + d] = (1.0f - zz) * nn + zz * hpv;
        }
        gbar(gr_cnt, (uint)(64 * t + 32));

        // ---- P2: target a-slice q*128 from full h[b] ----
        scrF[tid] = h_hist[(size_t)t * 32768 + (size_t)b * 512 + tid];
        __syncthreads();
        {
            int a = tid & 127, dq = tid >> 7;
            const uint* wq = WqT + (size_t)(dq * 64) * 512 + q * 128 + a;
            float acc = 0.f;
#pragma unroll 8
            for (int i = 0; i < 64; ++i) {
                uint w = wq[(size_t)i * 512];
                acc = fmaf(bfl(w), scrF[(dq * 64 + i) * 2 + 0],
                           fmaf(bfh(w), scrF[(dq * 64 + i) * 2 + 1], acc));
            }
            scrF[512 + tid] = acc;
        }
        __syncthreads();
        if (tid < 128)
            scrF[1024 + tid] = scrF[512 + tid] + scrF[640 + tid] +
                               scrF[768 + tid] + scrF[896 + tid];
        if (tid >= 128 && tid < 256) scrF[1152 + (tid - 128)] = v_att[q * 128 + (tid - 128)];
        if (tid >= 256) scrF[1280 + (tid - 256)] = mask[b * 256 + (tid - 256)];
        __syncthreads();

        // ---- P3: partial energy over a-slice, all 256 s ----
        {
            int s = tid & 255, hf = tid >> 8;
            int sw = (s ^ (s >> 3)) & 7;
            float acc = 0.f;
#pragma unroll
            for (int c8 = 0; c8 < 8; ++c8) {
                int ch = hf * 8 + c8;
                uint4 pv = *(const uint4*)&preT[s * 128 + ((ch ^ sw) << 3)];
                int ab = ch * 8;
                acc += scrF[1152 + ab + 0] * tanh_fast(bfl(pv.x) + scrF[1024 + ab + 0]);
                acc += scrF[1152 + ab + 1] * tanh_fast(bfh(pv.x) + scrF[1024 + ab + 1]);
                acc += scrF[1152 + ab + 2] * tanh_fast(bfl(pv.y) + scrF[1024 + ab + 2]);
                acc += scrF[1152 + ab + 3] * tanh_fast(bfh(pv.y) + scrF[1024 + ab + 3]);
                acc += scrF[1152 + ab + 4] * tanh_fast(bfl(pv.z) + scrF[1024 + ab + 4]);
                acc += scrF[1152 + ab + 5] * tanh_fast(bfh(pv.z) + scrF[1024 + ab + 5]);
                acc += scrF[1152 + ab + 6] * tanh_fast(bfl(pv.w) + scrF[1024 + ab + 6]);
                acc += scrF[1152 + ab + 7] * tanh_fast(bfh(pv.w) + scrF[1024 + ab + 7]);
            }
            scrF[1536 + tid] = acc;
        }
        __syncthreads();
        if (tid < 256)
            pe_buf[(size_t)b * 1024 + q * 256 + tid] = scrF[1536 + tid] + scrF[1792 + tid];
        gbar(cl_cnt, (uint)(4 * t + 4));

        // ---- P4: softmax (redundant per cluster block) + ctx GEMV e-slice ----
        {
            int s2 = tid & 255;
            const float* peb = pe_buf + (size_t)b * 1024;
            float e = peb[s2] + peb[256 + s2] + peb[512 + s2] + peb[768 + s2];
            float mk = scrF[1280 + s2];
            e = e * (1.0f - mk) + mk * (-1e6f);
            float mx = e;
#pragma unroll
            for (int off = 1; off < 64; off <<= 1) mx = fmaxf(mx, __shfl_xor(mx, off));
            if (lane == 0) scrF[2816 + wid] = mx;
            __syncthreads();
            mx = scrF[2816];
#pragma unroll
            for (int w2 = 1; w2 < 8; ++w2) mx = fmaxf(mx, scrF[2816 + w2]);
            float ex = __expf(e - mx);
            float sm = ex;
#pragma unroll
            for (int off = 1; off < 64; off <<= 1) sm += __shfl_xor(sm, off);
            if (lane == 0) scrF[2824 + wid] = sm;
            __syncthreads();
            sm = scrF[2824] + scrF[2825] + scrF[2826] + scrF[2827];
            float sc = ex / sm;
            scrF[2048 + s2] = sc;
            if (q == 0 && tid < 256) cout[((size_t)t * 64 + b) * 256 + tid] = sc;
        }
        __syncthreads();
        {
            int e_l = tid & 127, sq = tid >> 7;
            float acc = 0.f;
#pragma unroll 8
            for (int i = 0; i < 64; ++i) {
                int ss = sq * 64 + i;
                float cv = __uint_as_float(((uint)ctxT[ss * 128 + e_l]) << 16);
                acc = fmaf(scrF[2048 + ss], cv, acc);
            }
            scrF[2304 + tid] = acc;
        }
        __syncthreads();
        if (tid < 128) {
            float val = scrF[2304 + tid] + scrF[2432 + tid] +
                        scrF[2560 + tid] + scrF[2688 + tid];
            ctx_hist[(size_t)t * 32768 + (size_t)b * 512 + q * 128 + tid] = val;
        }
        gbar(gr_cnt, (uint)(64 * t + 64));
    }
}

// ---------------- batched copy gate ----------------
__global__ __launch_bounds__(256) void k_copy(
    const float* __restrict__ h_hist, const float* __restrict__ ctx_hist,
    const float* __restrict__ W_copy, const float* __restrict__ b_copy,
    float* __restrict__ out)
{
    const int tid = threadIdx.x;
    const int lane = tid & 63;
    const int tb = blockIdx.x * 4 + (tid >> 6);
    const float* hp = h_hist + (size_t)tb * DD;
    const float* cp = ctx_hist + (size_t)tb * DD;
    float acc = 0.f;
#pragma unroll
    for (int jj = 0; jj < 8; ++jj) {
        int k = lane + 64 * jj;
        acc = fmaf(hp[k], W_copy[k], acc);
        acc = fmaf(cp[k], W_copy[512 + k], acc);
    }
#pragma unroll
    for (int off = 1; off < 64; off <<= 1) acc += __shfl_xor(acc, off);
    if (lane == 0) out[tb] = sigmf(acc + b_copy[0]);
}

// ---------------- tail outputs ----------------
__global__ void k_final(const float* __restrict__ h_hist,
                        const float* __restrict__ ctx_hist,
                        float* __restrict__ dout)
{
    int idx = blockIdx.x * 256 + threadIdx.x;
    if (idx < 32768) {
        dout[1050624 + idx] = h_hist[31 * 32768 + idx];
    } else if (idx < 49152) {
        int i2 = idx - 32768;
        dout[1083392 + i2] = dout[524288 + 507904 + i2];
    } else {
        int i2 = idx - 49152;
        dout[1099776 + i2] = ctx_hist[31 * 32768 + i2];
    }
}

extern "C" void kernel_launch(void* const* d_in, const int* in_sizes, int n_in,
                              void* d_out, int out_size, void* d_ws, size_t ws_size,
                              hipStream_t stream)
{
    (void)in_sizes; (void)n_in; (void)out_size; (void)ws_size;
    const int*   ids      = (const int*)d_in[0];
    const float* hidden   = (const float*)d_in[1];
    const float* context  = (const float*)d_in[2];
    const float* mask     = (const float*)d_in[3];
    const float* init_att = (const float*)d_in[4];
    const float* emb_t    = (const float*)d_in[5];
    const float* W_ih     = (const float*)d_in[6];
    const float* W_hh     = (const float*)d_in[7];
    const float* b_ih     = (const float*)d_in[8];
    const float* b_hh     = (const float*)d_in[9];
    const float* W_pre    = (const float*)d_in[10];
    const float* b_pre    = (const float*)d_in[11];
    const float* W_q      = (const float*)d_in[12];
    const float* v_att    = (const float*)d_in[13];
    const float* W_copy   = (const float*)d_in[14];
    const float* b_copy   = (const float*)d_in[15];
    const float* W_read   = (const float*)d_in[16];
    const float* b_read   = (const float*)d_in[17];
    float* out = (float*)d_out;
    float* ws = (float*)d_ws;

    ushort* preb    = (ushort*)ws;
    float* gxe      = ws + 4194304;
    float* h_hist   = ws + 7340032;
    float* ctx_hist = ws + 8388608;
    float* pe_buf   = ws + 9437184;
    uint* Wpk       = (uint*)(ws + 9502720);
    uint* WqT       = (uint*)(ws + 10289152);
    uint* cnt       = (uint*)(ws + 10420224);
    float* cout     = out + 524288;

    hipMemsetAsync(cnt, 0, 16384, stream);
    // pre = ctx_t @ W_pre^T + b_pre  (bf16 out)
    mgemm<0><<<dim3(256, 8), 256, 0, stream>>>(context, nullptr, nullptr, nullptr,
                                               W_pre, b_pre, (void*)preb, 512, 512);
    // gxe = emb @ W_ih[:, :512]^T + b_ih  (f32 out, ldc 1536)
    mgemm<1><<<dim3(32, 24), 256, 0, stream>>>(emb_t, nullptr, nullptr, ids,
                                               W_ih, b_ih, (void*)gxe, 1024, 512);
    wprep2<<<1792, 512, 0, stream>>>(W_ih, W_hh, W_q, Wpk, WqT);
    {
        void* args[] = {
            (void*)&gxe, (void*)&hidden, (void*)&init_att, (void*)&context,
            (void*)&mask, (void*)&v_att, (void*)&b_hh, (void*)&preb,
            (void*)&Wpk, (void*)&WqT,
            (void*)&h_hist, (void*)&ctx_hist, (void*)&pe_buf, (void*)&cnt,
            (void*)&cout
        };
        hipLaunchCooperativeKernel((void*)k_steps, dim3(256), dim3(512), args, 0,
                                   stream);
    }
    // readout + maxout
    mgemm<2><<<dim3(32, 8), 256, 0, stream>>>(emb_t, h_hist, ctx_hist, ids,
                                              W_read, b_read, (void*)out, 1536, 1536);
    k_copy<<<512, 256, 0, stream>>>(h_hist, ctx_hist, W_copy, b_copy, out + 1048576);
    k_final<<<320, 256, 0, stream>>>(h_hist, ctx_hist, out);
}